// Round 10
// baseline (181.854 us; speedup 1.0000x reference)
//
#include <hip/hip_runtime.h>

#define T_TOK 4096
#define DIM   1024
#define FDIM  2048
#define NEXP  8

typedef unsigned short u16;
typedef unsigned int   u32;
typedef __bf16 bf16x8 __attribute__((ext_vector_type(8)));
typedef float  f32x4  __attribute__((ext_vector_type(4)));

__device__ __forceinline__ u16 f2b(float f) {
  __bf16 b = (__bf16)f;
  return __builtin_bit_cast(u16, b);
}
__device__ __forceinline__ u32 pk(float a, float b) {
  return (u32)f2b(a) | ((u32)f2b(b) << 16);
}

// async global->LDS, 16B/lane; LDS dest wave-uniform base + lane*16
#define GLOAD16(gsrc, ldst) \
  __builtin_amdgcn_global_load_lds((const __attribute__((address_space(1))) void*)(gsrc), \
                                   (__attribute__((address_space(3))) void*)(ldst), 16, 0, 0)

__device__ __forceinline__ int xcd_swz(int b, int nwg) {
  return (b & 7) * (nwg >> 3) + (b >> 3);
}

// ---------------- gating (1 token/wave, fused x->bf16) ----------------
__global__ __launch_bounds__(256) void gating_kernel(
    const float* __restrict__ x, const float* __restrict__ wg,
    int* __restrict__ tokexp, float* __restrict__ tokwgt, u16* __restrict__ xb)
{
  int wid = threadIdx.x >> 6, lane = threadIdx.x & 63;
  int t = blockIdx.x * 4 + wid;
  const float4* xr = (const float4*)(x + (size_t)t * DIM) + lane * 4;
  float4 xv[4];
#pragma unroll
  for (int j = 0; j < 4; ++j) xv[j] = xr[j];

  u16* xd = xb + (size_t)t * DIM + lane * 16;
  uint4 lo, hi;
  lo.x = pk(xv[0].x, xv[0].y); lo.y = pk(xv[0].z, xv[0].w);
  lo.z = pk(xv[1].x, xv[1].y); lo.w = pk(xv[1].z, xv[1].w);
  hi.x = pk(xv[2].x, xv[2].y); hi.y = pk(xv[2].z, xv[2].w);
  hi.z = pk(xv[3].x, xv[3].y); hi.w = pk(xv[3].z, xv[3].w);
  *(uint4*)xd = lo;
  *(uint4*)(xd + 8) = hi;

  float logit[NEXP];
#pragma unroll
  for (int e = 0; e < NEXP; ++e) {
    const float4* wr = (const float4*)(wg + (size_t)e * DIM) + lane * 4;
    float s = 0.f;
#pragma unroll
    for (int j = 0; j < 4; ++j) {
      float4 wv = wr[j];
      s += xv[j].x * wv.x + xv[j].y * wv.y + xv[j].z * wv.z + xv[j].w * wv.w;
    }
#pragma unroll
    for (int d = 32; d > 0; d >>= 1) s += __shfl_down(s, d, 64);
    logit[e] = s;
  }
  if (lane == 0) {
    float mx = -1e30f;
#pragma unroll
    for (int e = 0; e < NEXP; ++e) mx = fmaxf(mx, logit[e]);
    float p[NEXP]; float s = 0.f;
#pragma unroll
    for (int e = 0; e < NEXP; ++e) { p[e] = expf(logit[e] - mx); s += p[e]; }
    float inv = 1.f / s;
#pragma unroll
    for (int e = 0; e < NEXP; ++e) p[e] *= inv;
    int e0 = 0;
#pragma unroll
    for (int e = 1; e < NEXP; ++e) if (p[e] > p[e0]) e0 = e;
    int e1 = (e0 == 0) ? 1 : 0;
#pragma unroll
    for (int e = 0; e < NEXP; ++e) if (e != e0 && p[e] > p[e1]) e1 = e;
    tokexp[2 * t]     = e0;
    tokexp[2 * t + 1] = e1;
    tokwgt[2 * t]     = p[e0];
    tokwgt[2 * t + 1] = p[e1];
  }
}

// ---------------- plan: single block; histogram + offsets + stable scatter --------
__global__ __launch_bounds__(256) void plan_kernel(
    const int* __restrict__ tokexp,
    int* __restrict__ counts, int* __restrict__ offsets,
    int* __restrict__ tok, int* __restrict__ slot)
{
  __shared__ int hist[256][NEXP];
  __shared__ int soff[NEXP];
  int tid = threadIdx.x;
  int ex[32];
  int loc[NEXP];
#pragma unroll
  for (int e = 0; e < NEXP; ++e) loc[e] = 0;
#pragma unroll
  for (int j = 0; j < 32; ++j) {
    ex[j] = tokexp[tid * 32 + j];
#pragma unroll
    for (int e = 0; e < NEXP; ++e) loc[e] += (ex[j] == e);
  }
#pragma unroll
  for (int e = 0; e < NEXP; ++e) hist[tid][e] = loc[e];
  __syncthreads();
  if (tid < NEXP) {
    int s = 0;
    for (int i = 0; i < 256; ++i) { int v = hist[i][tid]; hist[i][tid] = s; s += v; }
    counts[tid] = s;
  }
  __syncthreads();
  if (tid == 0) {
    int s = 0;
#pragma unroll
    for (int e = 0; e < NEXP; ++e) { soff[e] = s; offsets[e] = s; s += counts[e]; }
  }
  __syncthreads();
  int cur[NEXP];
#pragma unroll
  for (int e = 0; e < NEXP; ++e) cur[e] = soff[e] + hist[tid][e];
#pragma unroll
  for (int j = 0; j < 32; ++j) {
    int a = tid * 32 + j;
    int r = 0;
#pragma unroll
    for (int e = 0; e < NEXP; ++e) if (ex[j] == e) r = cur[e]++;
    tok[r] = a >> 1;
    slot[a] = r;
  }
}

// ---------------- prep: convert w1 (blocks 0..8191) + transpose w2 (8192..12287) --
__global__ __launch_bounds__(256) void prep_kernel(
    const float* __restrict__ w1, u16* __restrict__ w1b,
    const float* __restrict__ w2, u16* __restrict__ w2t)
{
  __shared__ float tile[64][65];
  int b = blockIdx.x;
  int tid = threadIdx.x;
  if (b < 8192) {
    // fp32 -> bf16, 8 elems/thread
    size_t i = (size_t)b * 256 + tid;
    const float4* s = (const float4*)(w1 + i * 8);
    float4 v0 = s[0], v1 = s[1];
    uint4 w;
    w.x = pk(v0.x, v0.y); w.y = pk(v0.z, v0.w);
    w.z = pk(v1.x, v1.y); w.w = pk(v1.z, v1.w);
    *(uint4*)(w1b + i * 8) = w;
    return;
  }
  int bb = b - 8192;                 // 4096 tiles: [e][ft 0..31][dt 0..15]
  int e = bb >> 9;
  int r = bb & 511;
  int d0 = (r & 15) * 64;
  int f0 = (r >> 4) * 64;
  int fi = tid >> 2;                 // 0..63
  int c4 = tid & 3;                  // 0..3
  const float* src = w2 + ((size_t)e * FDIM + f0 + fi) * DIM + d0;
#pragma unroll
  for (int i = 0; i < 4; ++i) {
    int col = (c4 + i * 4) * 4;
    float4 v = *(const float4*)(src + col);
    tile[fi][col] = v.x; tile[fi][col + 1] = v.y;
    tile[fi][col + 2] = v.z; tile[fi][col + 3] = v.w;
  }
  __syncthreads();
  u16* dst = w2t + ((size_t)e * DIM + d0) * FDIM + f0;
#pragma unroll
  for (int i = 0; i < 2; ++i) {
    int id = i * 256 + tid;
    int d = id >> 3;
    int c = id & 7;
    uint4 w;
    w.x = pk(tile[c * 8 + 0][d], tile[c * 8 + 1][d]);
    w.y = pk(tile[c * 8 + 2][d], tile[c * 8 + 3][d]);
    w.z = pk(tile[c * 8 + 4][d], tile[c * 8 + 5][d]);
    w.w = pk(tile[c * 8 + 6][d], tile[c * 8 + 7][d]);
    *(uint4*)(dst + (size_t)d * FDIM + c * 8) = w;
  }
}

// ========== grouped 288x256 4-phase GEMM (16x16x32 MFMA, K per block = 1024) =====
// BM=288, BN=256, BK=64, 8 waves (2Mx4N, wave tile 144x64 = 9 M-frags), raw
// s_barrier + counted vmcnt(4) + setprio. 4 phases per K-tile-pair (halved
// barrier count vs 8-phase; per-phase interleave of ds_read/stage/MFMA kept).
// Swizzle: LDS 16B chunk c of row r holds source chunk c^(r&7), staged via
// pre-swizzled per-lane global source (linear LDS dest), read with same XOR.
template<int GELU, int GATHER, int KA, int KB, int NT, int KS, int CLD>
__global__ __launch_bounds__(512, 2) void gemm8_kernel(
    const u16* __restrict__ Amat, const u16* __restrict__ Bmat,
    const int* __restrict__ tok, const int* __restrict__ counts,
    const int* __restrict__ offsets, u16* __restrict__ Cmat)
{
  const int NTK = NT * KS;   // 8 for both instantiations
  int bid = blockIdx.x;
  int e, yt, xt, ks;
  if (bid < 256) {
    int t0 = xcd_swz(bid, 256);
    xt = t0 % NT;
    ks = (t0 / NT) % KS;
    yt = (t0 / NTK) & 3;
    e  = t0 / (NTK * 4);
  } else {
    int s = bid - 256;                 // spare tiles: yt=4
    xt = s % NT;
    ks = (s / NT) % KS;
    yt = 4;
    e  = s / NTK;
  }

  int Me = counts[e];
  if (Me == 0) return;
  int mbase = yt * 288;
  if (mbase >= Me) return;
  int nbase = xt * 256;
  int off = offsets[e];
  int koff = ks * 1024;
  if (KS == 2 && ks == 1) Cmat += (size_t)8192 * CLD;

  __shared__ u16 Als[2][288 * 64];   // 2 x 36 KB
  __shared__ u16 Bls[2][256 * 64];   // 2 x 32 KB
  __shared__ u16 scrap[512];         // dummy-stage target (1 KB)

  int tid = threadIdx.x, lane = tid & 63, wid = tid >> 6;
  int wr = wid >> 2;       // 0..1  (M half: 144 rows)
  int wc = wid & 3;        // 0..3  (N quarter: 64 cols)
  int fr = lane & 15, kg = lane >> 4;
  int l8 = lane >> 3, l7 = lane & 7;
  int xorc = (l7 ^ l8) * 8;           // pre-swizzled source column (elems)

  const u16* sA[5];
  const u16* sB[4];
#pragma unroll
  for (int c = 0; c < 4; ++c) {
    int r = (c * 4096 + tid * 8) >> 6;                  // 0..255
    int gr = mbase + r; if (gr >= Me) gr = Me - 1;
    int arow = GATHER ? tok[off + gr] : (off + gr);
    sA[c] = Amat + (size_t)arow * KA + koff + xorc;
    sB[c] = Bmat + (size_t)e * FDIM * DIM + (size_t)(nbase + r) * KB + koff + xorc;
  }
  {
    int r = (tid < 256) ? (256 + (tid >> 3)) : 0;       // 256..287 or dummy
    int gr = mbase + r; if (gr >= Me) gr = Me - 1;
    int arow = GATHER ? tok[off + gr] : (off + gr);
    sA[4] = Amat + (size_t)arow * KA + koff + xorc;
  }
  int a4real = (tid < 256);                              // wave-uniform
  u16* a4dst[2];
  a4dst[0] = a4real ? &Als[0][4 * 4096 + wid * 512] : scrap;
  a4dst[1] = a4real ? &Als[1][4 * 4096 + wid * 512] : scrap;

#define STG_A(b, t_) do { \
    GLOAD16(sA[0] + (size_t)(t_) * 64, &Als[(b)][0 * 4096 + wid * 512]); \
    GLOAD16(sA[1] + (size_t)(t_) * 64, &Als[(b)][1 * 4096 + wid * 512]); \
    GLOAD16(sA[2] + (size_t)(t_) * 64, &Als[(b)][2 * 4096 + wid * 512]); \
    GLOAD16(sA[3] + (size_t)(t_) * 64, &Als[(b)][3 * 4096 + wid * 512]); \
    GLOAD16(sA[4] + (size_t)(t_) * 64, a4dst[(b)]); } while (0)
#define STG_B(b, t_) do { \
    GLOAD16(sB[0] + (size_t)(t_) * 64, &Bls[(b)][0 * 4096 + wid * 512]); \
    GLOAD16(sB[1] + (size_t)(t_) * 64, &Bls[(b)][1 * 4096 + wid * 512]); \
    GLOAD16(sB[2] + (size_t)(t_) * 64, &Bls[(b)][2 * 4096 + wid * 512]); \
    GLOAD16(sB[3] + (size_t)(t_) * 64, &Bls[(b)][3 * 4096 + wid * 512]); } while (0)
#define DUM2 do { GLOAD16(sA[0], scrap); GLOAD16(sA[0], scrap); } while (0)
#define DUM4 do { DUM2; DUM2; } while (0)
#define DUM5 do { DUM4; GLOAD16(sA[0], scrap); } while (0)
#define VM4 asm volatile("s_waitcnt vmcnt(4)" ::: "memory")

  f32x4 acc[9][4];
#pragma unroll
  for (int m = 0; m < 9; ++m)
#pragma unroll
    for (int n = 0; n < 4; ++n)
      acc[m][n] = (f32x4){0.f, 0.f, 0.f, 0.f};

  bf16x8 bfr[4][2];
  int cq0 = ((0 * 4 + kg) ^ (fr & 7)) * 8;   // K 0..31 chunk (elems)
  int cq1 = ((1 * 4 + kg) ^ (fr & 7)) * 8;   // K 32..63 chunk

  // 4-phase: phase covers frags [F0,F1) of buf b; RB=1 reloads all B frags.
  // {ds_read / (B) / STAGE / VW} -> barrier -> setprio MFMA -> barrier.
#define PHASE4(b, F0, F1, RB, STAGE, VW) do { \
    bf16x8 af[5][2]; \
    _Pragma("unroll") \
    for (int j = 0; j < (F1) - (F0); ++j) { \
      int arow = (wr * 144 + ((F0) + j) * 16 + fr) * 64; \
      af[j][0] = *(const bf16x8*)&Als[(b)][arow + cq0]; \
      af[j][1] = *(const bf16x8*)&Als[(b)][arow + cq1]; \
    } \
    if (RB) { \
      _Pragma("unroll") \
      for (int ni = 0; ni < 4; ++ni) { \
        int brow = (wc * 64 + ni * 16 + fr) * 64; \
        bfr[ni][0] = *(const bf16x8*)&Bls[(b)][brow + cq0]; \
        bfr[ni][1] = *(const bf16x8*)&Bls[(b)][brow + cq1]; \
      } \
    } \
    STAGE; \
    VW; \
    __builtin_amdgcn_s_barrier(); \
    __builtin_amdgcn_s_setprio(1); \
    _Pragma("unroll") \
    for (int j = 0; j < (F1) - (F0); ++j) \
    _Pragma("unroll") \
    for (int ni = 0; ni < 4; ++ni) { \
      acc[(F0) + j][ni] = __builtin_amdgcn_mfma_f32_16x16x32_bf16(af[j][0], bfr[ni][0], acc[(F0) + j][ni], 0, 0, 0); \
      acc[(F0) + j][ni] = __builtin_amdgcn_mfma_f32_16x16x32_bf16(af[j][1], bfr[ni][1], acc[(F0) + j][ni], 0, 0, 0); \
    } \
    __builtin_amdgcn_s_setprio(0); \
    __builtin_amdgcn_s_barrier(); \
  } while (0)

  const int nt = 16;  // K-tiles of 64 (K per block = 1024)

  // prologue: tile0 full -> buf0; tile1 B -> buf1; publish tile0 (VM4 leaves buf1 B)
  STG_A(0, 0); STG_B(0, 0);
  STG_B(1, 1);
  VM4;
  __builtin_amdgcn_s_barrier();

  for (int j = 0; j < nt / 2; ++j) {
    int t1 = 2 * j + 1, t2 = 2 * j + 2, t3 = 2 * j + 3;
    bool f2 = t2 < nt, f3 = t3 < nt;
    // P1: buf0 frags 0-3 + B; issue A(1,t1)
    PHASE4(0, 0, 4, 1, STG_A(1, t1), (void)0);
    // P2: buf0 frags 4-8; issue B(0,t2); VM4 completes buf1's A+B (9 oldest)
    PHASE4(0, 4, 9, 0, if (f2) STG_B(0, t2); else DUM4, VM4);
    // P3: buf1 frags 0-3 + B; issue A(0,t2)
    PHASE4(1, 0, 4, 1, if (f2) STG_A(0, t2); else DUM5, (void)0);
    // P4: buf1 frags 4-8; issue B(1,t3); VM4 completes buf0-t2's A+B
    PHASE4(1, 4, 9, 0, if (f3) STG_B(1, t3); else DUM4, VM4);
  }

  // epilogue (16x16 C/D: col=lane&15 -> fr, row=kg*4+r within frag)
  int rb = kg * 4;
#pragma unroll
  for (int mi = 0; mi < 9; ++mi) {
#pragma unroll
    for (int r = 0; r < 4; ++r) {
      int row = wr * 144 + mi * 16 + rb + r;
      if (mbase + row < Me) {
        u16* dst = Cmat + (size_t)(off + mbase + row) * CLD + nbase + wc * 64;
#pragma unroll
        for (int ni = 0; ni < 4; ++ni) {
          float v = acc[mi][ni][r];
          if (GELU) v = 0.5f * v * (1.f + erff(v * 0.70710678118654752f));
          dst[ni * 16 + fr] = f2b(v);
        }
      }
    }
  }
#undef STG_A
#undef STG_B
#undef DUM2
#undef DUM4
#undef DUM5
#undef VM4
#undef PHASE4
}

// ---------------- combine: y[t] = w0*(O0[s0]+O1[s0]) + w1*(O0[s1]+O1[s1]) --------
__global__ __launch_bounds__(256) void combine_kernel(
    const u16* __restrict__ O, const int* __restrict__ slot,
    const float* __restrict__ tokwgt, float* __restrict__ y)
{
  int idx = blockIdx.x * 256 + threadIdx.x;
  int t = idx >> 7;
  int d8 = (idx & 127) << 3;
  int s0 = slot[2 * t], s1 = slot[2 * t + 1];
  float w0 = tokwgt[2 * t], w1 = tokwgt[2 * t + 1];
  const u16* O1p = O + (size_t)8192 * DIM;
  bf16x8 a0 = *(const bf16x8*)(O + (size_t)s0 * DIM + d8);
  bf16x8 a1 = *(const bf16x8*)(O1p + (size_t)s0 * DIM + d8);
  bf16x8 b0 = *(const bf16x8*)(O + (size_t)s1 * DIM + d8);
  bf16x8 b1 = *(const bf16x8*)(O1p + (size_t)s1 * DIM + d8);
  float* dst = y + (size_t)t * DIM + d8;
  float4 o0, o1;
  o0.x = w0 * ((float)a0[0] + (float)a1[0]) + w1 * ((float)b0[0] + (float)b1[0]);
  o0.y = w0 * ((float)a0[1] + (float)a1[1]) + w1 * ((float)b0[1] + (float)b1[1]);
  o0.z = w0 * ((float)a0[2] + (float)a1[2]) + w1 * ((float)b0[2] + (float)b1[2]);
  o0.w = w0 * ((float)a0[3] + (float)a1[3]) + w1 * ((float)b0[3] + (float)b1[3]);
  o1.x = w0 * ((float)a0[4] + (float)a1[4]) + w1 * ((float)b0[4] + (float)b1[4]);
  o1.y = w0 * ((float)a0[5] + (float)a1[5]) + w1 * ((float)b0[5] + (float)b1[5]);
  o1.z = w0 * ((float)a0[6] + (float)a1[6]) + w1 * ((float)b0[6] + (float)b1[6]);
  o1.w = w0 * ((float)a0[7] + (float)a1[7]) + w1 * ((float)b0[7] + (float)b1[7]);
  *(float4*)dst = o0;
  *(float4*)(dst + 4) = o1;
}

extern "C" void kernel_launch(void* const* d_in, const int* in_sizes, int n_in,
                              void* d_out, int out_size, void* d_ws, size_t ws_size,
                              hipStream_t stream)
{
  const float* x  = (const float*)d_in[0];
  const float* wg = (const float*)d_in[1];
  const float* w1 = (const float*)d_in[2];
  const float* w2 = (const float*)d_in[3];
  float* y = (float*)d_out;

  char* ws = (char*)d_ws;
  size_t o = 0;
  u16* h      = (u16*)(ws + o);   o += (size_t)8192 * FDIM * 2;        // 33.55 MB
  u16* w2t    = (u16*)(ws + o);   o += (size_t)NEXP * DIM * FDIM * 2;  // 33.55 MB
  u16* xb     = (u16*)(ws + o);   o += (size_t)T_TOK * DIM * 2;        //  8.39 MB
  u16* w1b    = (u16*)(ws + o);   o += (size_t)NEXP * FDIM * DIM * 2;  // 33.55 MB
  u16* O      = w1b;  // aliased: w1b dead after fc1; O = 2 x [8192][DIM] bf16
  int*   tokexp = (int*)(ws + o); o += (size_t)T_TOK * 2 * 4;
  float* tokwgt = (float*)(ws + o); o += (size_t)T_TOK * 2 * 4;
  int*   tok    = (int*)(ws + o); o += (size_t)T_TOK * 2 * 4;
  int*   slot   = (int*)(ws + o); o += (size_t)T_TOK * 2 * 4;
  int*   counts = (int*)(ws + o); o += 128;
  int*   offsets= (int*)(ws + o); o += 128;

  gating_kernel<<<T_TOK / 4, 256, 0, stream>>>(x, wg, tokexp, tokwgt, xb);
  plan_kernel<<<1, 256, 0, stream>>>(tokexp, counts, offsets, tok, slot);

  // convert w1 (8192 blocks) + transpose w2 (4096 blocks) in one dispatch
  prep_kernel<<<8192 + 4096, 256, 0, stream>>>(w1, w1b, w2, w2t);

  // fc1: h = gelu(gather(xb) @ w1b^T)   [NT=8, KS=1] -> blocks 0..255 working
  gemm8_kernel<1, 1, DIM, DIM, 8, 1, FDIM>
      <<<320, 512, 0, stream>>>(xb, w1b, tok, counts, offsets, h);
  // fc2: O[ks] = h[:, ks*1024:+1024] @ w2t[:, ks*1024:+1024]^T  [NT=4, KS=2]
  gemm8_kernel<0, 0, FDIM, FDIM, 4, 2, DIM>
      <<<320, 512, 0, stream>>>(h, w2t, tok, counts, offsets, O);

  combine_kernel<<<T_TOK * DIM / 8 / 256, 256, 0, stream>>>(O, slot, tokwgt, y);
}

// Round 11
// 167.792 us; speedup vs baseline: 1.0838x; 1.0838x over previous
//
#include <hip/hip_runtime.h>

#define T_TOK 4096
#define DIM   1024
#define FDIM  2048
#define NEXP  8

typedef unsigned short u16;
typedef unsigned int   u32;
typedef __bf16 bf16x8 __attribute__((ext_vector_type(8)));
typedef float  f32x4  __attribute__((ext_vector_type(4)));

__device__ __forceinline__ u16 f2b(float f) {
  __bf16 b = (__bf16)f;
  return __builtin_bit_cast(u16, b);
}
__device__ __forceinline__ u32 pk(float a, float b) {
  return (u32)f2b(a) | ((u32)f2b(b) << 16);
}

#define GLOAD16(gsrc, ldst) \
  __builtin_amdgcn_global_load_lds((const __attribute__((address_space(1))) void*)(gsrc), \
                                   (__attribute__((address_space(3))) void*)(ldst), 16, 0, 0)

__device__ __forceinline__ int xcd_swz(int b, int nwg) {
  return (b & 7) * (nwg >> 3) + (b >> 3);
}

// ---------------- gating (1 token/wave, fused x->bf16) ----------------
__global__ __launch_bounds__(256) void gating_kernel(
    const float* __restrict__ x, const float* __restrict__ wg,
    int* __restrict__ tokexp, float* __restrict__ tokwgt, u16* __restrict__ xb)
{
  int wid = threadIdx.x >> 6, lane = threadIdx.x & 63;
  int t = blockIdx.x * 4 + wid;
  const float4* xr = (const float4*)(x + (size_t)t * DIM) + lane * 4;
  float4 xv[4];
#pragma unroll
  for (int j = 0; j < 4; ++j) xv[j] = xr[j];

  u16* xd = xb + (size_t)t * DIM + lane * 16;
  uint4 lo, hi;
  lo.x = pk(xv[0].x, xv[0].y); lo.y = pk(xv[0].z, xv[0].w);
  lo.z = pk(xv[1].x, xv[1].y); lo.w = pk(xv[1].z, xv[1].w);
  hi.x = pk(xv[2].x, xv[2].y); hi.y = pk(xv[2].z, xv[2].w);
  hi.z = pk(xv[3].x, xv[3].y); hi.w = pk(xv[3].z, xv[3].w);
  *(uint4*)xd = lo;
  *(uint4*)(xd + 8) = hi;

  float logit[NEXP];
#pragma unroll
  for (int e = 0; e < NEXP; ++e) {
    const float4* wr = (const float4*)(wg + (size_t)e * DIM) + lane * 4;
    float s = 0.f;
#pragma unroll
    for (int j = 0; j < 4; ++j) {
      float4 wv = wr[j];
      s += xv[j].x * wv.x + xv[j].y * wv.y + xv[j].z * wv.z + xv[j].w * wv.w;
    }
#pragma unroll
    for (int d = 32; d > 0; d >>= 1) s += __shfl_down(s, d, 64);
    logit[e] = s;
  }
  if (lane == 0) {
    float mx = -1e30f;
#pragma unroll
    for (int e = 0; e < NEXP; ++e) mx = fmaxf(mx, logit[e]);
    float p[NEXP]; float s = 0.f;
#pragma unroll
    for (int e = 0; e < NEXP; ++e) { p[e] = expf(logit[e] - mx); s += p[e]; }
    float inv = 1.f / s;
#pragma unroll
    for (int e = 0; e < NEXP; ++e) p[e] *= inv;
    int e0 = 0;
#pragma unroll
    for (int e = 1; e < NEXP; ++e) if (p[e] > p[e0]) e0 = e;
    int e1 = (e0 == 0) ? 1 : 0;
#pragma unroll
    for (int e = 0; e < NEXP; ++e) if (e != e0 && p[e] > p[e1]) e1 = e;
    tokexp[2 * t]     = e0;
    tokexp[2 * t + 1] = e1;
    tokwgt[2 * t]     = p[e0];
    tokwgt[2 * t + 1] = p[e1];
  }
}

// ---------------- plan: single block; histogram + offsets + stable scatter --------
__global__ __launch_bounds__(256) void plan_kernel(
    const int* __restrict__ tokexp,
    int* __restrict__ counts, int* __restrict__ offsets,
    int* __restrict__ tok, int* __restrict__ slot)
{
  __shared__ int hist[256][NEXP];
  __shared__ int soff[NEXP];
  int tid = threadIdx.x;
  int ex[32];
  int loc[NEXP];
#pragma unroll
  for (int e = 0; e < NEXP; ++e) loc[e] = 0;
#pragma unroll
  for (int j = 0; j < 32; ++j) {
    ex[j] = tokexp[tid * 32 + j];
#pragma unroll
    for (int e = 0; e < NEXP; ++e) loc[e] += (ex[j] == e);
  }
#pragma unroll
  for (int e = 0; e < NEXP; ++e) hist[tid][e] = loc[e];
  __syncthreads();
  if (tid < NEXP) {
    int s = 0;
    for (int i = 0; i < 256; ++i) { int v = hist[i][tid]; hist[i][tid] = s; s += v; }
    counts[tid] = s;
  }
  __syncthreads();
  if (tid == 0) {
    int s = 0;
#pragma unroll
    for (int e = 0; e < NEXP; ++e) { soff[e] = s; offsets[e] = s; s += counts[e]; }
  }
  __syncthreads();
  int cur[NEXP];
#pragma unroll
  for (int e = 0; e < NEXP; ++e) cur[e] = soff[e] + hist[tid][e];
#pragma unroll
  for (int j = 0; j < 32; ++j) {
    int a = tid * 32 + j;
    int r = 0;
#pragma unroll
    for (int e = 0; e < NEXP; ++e) if (ex[j] == e) r = cur[e]++;
    tok[r] = a >> 1;
    slot[a] = r;
  }
}

// ---------------- prep: convert w1 (blocks 0..8191) + transpose w2 (8192..12287) --
__global__ __launch_bounds__(256) void prep_kernel(
    const float* __restrict__ w1, u16* __restrict__ w1b,
    const float* __restrict__ w2, u16* __restrict__ w2t)
{
  __shared__ float tile[64][65];
  int b = blockIdx.x;
  int tid = threadIdx.x;
  if (b < 8192) {
    size_t i = (size_t)b * 256 + tid;
    const float4* s = (const float4*)(w1 + i * 8);
    float4 v0 = s[0], v1 = s[1];
    uint4 w;
    w.x = pk(v0.x, v0.y); w.y = pk(v0.z, v0.w);
    w.z = pk(v1.x, v1.y); w.w = pk(v1.z, v1.w);
    *(uint4*)(w1b + i * 8) = w;
    return;
  }
  int bb = b - 8192;
  int e = bb >> 9;
  int r = bb & 511;
  int d0 = (r & 15) * 64;
  int f0 = (r >> 4) * 64;
  int fi = tid >> 2;
  int c4 = tid & 3;
  const float* src = w2 + ((size_t)e * FDIM + f0 + fi) * DIM + d0;
#pragma unroll
  for (int i = 0; i < 4; ++i) {
    int col = (c4 + i * 4) * 4;
    float4 v = *(const float4*)(src + col);
    tile[fi][col] = v.x; tile[fi][col + 1] = v.y;
    tile[fi][col + 2] = v.z; tile[fi][col + 3] = v.w;
  }
  __syncthreads();
  u16* dst = w2t + ((size_t)e * DIM + d0) * FDIM + f0;
#pragma unroll
  for (int i = 0; i < 2; ++i) {
    int id = i * 256 + tid;
    int d = id >> 3;
    int c = id & 7;
    uint4 w;
    w.x = pk(tile[c * 8 + 0][d], tile[c * 8 + 1][d]);
    w.y = pk(tile[c * 8 + 2][d], tile[c * 8 + 3][d]);
    w.z = pk(tile[c * 8 + 4][d], tile[c * 8 + 5][d]);
    w.w = pk(tile[c * 8 + 6][d], tile[c * 8 + 7][d]);
    *(uint4*)(dst + (size_t)d * FDIM + c * 8) = w;
  }
}

// ========== fc1: grouped 288x256 8-phase GEMM (r8 config, control) ===============
template<int GELU, int GATHER, int KA, int KB, int NT, int KS, int CLD>
__global__ __launch_bounds__(512, 2) void gemm8_kernel(
    const u16* __restrict__ Amat, const u16* __restrict__ Bmat,
    const int* __restrict__ tok, const int* __restrict__ counts,
    const int* __restrict__ offsets, u16* __restrict__ Cmat)
{
  const int NTK = NT * KS;
  int bid = blockIdx.x;
  int e, yt, xt, ks;
  if (bid < 256) {
    int t0 = xcd_swz(bid, 256);
    xt = t0 % NT;
    ks = (t0 / NT) % KS;
    yt = (t0 / NTK) & 3;
    e  = t0 / (NTK * 4);
  } else {
    int s = bid - 256;
    xt = s % NT;
    ks = (s / NT) % KS;
    yt = 4;
    e  = s / NTK;
  }

  int Me = counts[e];
  if (Me == 0) return;
  int mbase = yt * 288;
  if (mbase >= Me) return;
  int nbase = xt * 256;
  int off = offsets[e];
  int koff = ks * 1024;
  if (KS == 2 && ks == 1) Cmat += (size_t)8192 * CLD;

  __shared__ u16 Als[2][288 * 64];
  __shared__ u16 Bls[2][256 * 64];
  __shared__ u16 scrap[512];

  int tid = threadIdx.x, lane = tid & 63, wid = tid >> 6;
  int wr = wid >> 2;
  int wc = wid & 3;
  int fr = lane & 15, kg = lane >> 4;
  int l8 = lane >> 3, l7 = lane & 7;
  int xorc = (l7 ^ l8) * 8;

  const u16* sA[5];
  const u16* sB[4];
#pragma unroll
  for (int c = 0; c < 4; ++c) {
    int r = (c * 4096 + tid * 8) >> 6;
    int gr = mbase + r; if (gr >= Me) gr = Me - 1;
    int arow = GATHER ? tok[off + gr] : (off + gr);
    sA[c] = Amat + (size_t)arow * KA + koff + xorc;
    sB[c] = Bmat + (size_t)e * FDIM * DIM + (size_t)(nbase + r) * KB + koff + xorc;
  }
  {
    int r = (tid < 256) ? (256 + (tid >> 3)) : 0;
    int gr = mbase + r; if (gr >= Me) gr = Me - 1;
    int arow = GATHER ? tok[off + gr] : (off + gr);
    sA[4] = Amat + (size_t)arow * KA + koff + xorc;
  }
  int a4real = (tid < 256);
  u16* a4dst[2];
  a4dst[0] = a4real ? &Als[0][4 * 4096 + wid * 512] : scrap;
  a4dst[1] = a4real ? &Als[1][4 * 4096 + wid * 512] : scrap;

#define STG_A(b, t_) do { \
    GLOAD16(sA[0] + (size_t)(t_) * 64, &Als[(b)][0 * 4096 + wid * 512]); \
    GLOAD16(sA[1] + (size_t)(t_) * 64, &Als[(b)][1 * 4096 + wid * 512]); \
    GLOAD16(sA[2] + (size_t)(t_) * 64, &Als[(b)][2 * 4096 + wid * 512]); \
    GLOAD16(sA[3] + (size_t)(t_) * 64, &Als[(b)][3 * 4096 + wid * 512]); \
    GLOAD16(sA[4] + (size_t)(t_) * 64, a4dst[(b)]); } while (0)
#define STG_B0(b, t_) do { \
    GLOAD16(sB[0] + (size_t)(t_) * 64, &Bls[(b)][0 * 4096 + wid * 512]); \
    GLOAD16(sB[1] + (size_t)(t_) * 64, &Bls[(b)][1 * 4096 + wid * 512]); } while (0)
#define STG_B1(b, t_) do { \
    GLOAD16(sB[2] + (size_t)(t_) * 64, &Bls[(b)][2 * 4096 + wid * 512]); \
    GLOAD16(sB[3] + (size_t)(t_) * 64, &Bls[(b)][3 * 4096 + wid * 512]); } while (0)
#define DUM2 do { GLOAD16(sA[0], scrap); GLOAD16(sA[0], scrap); } while (0)
#define DUM5 do { DUM2; DUM2; GLOAD16(sA[0], scrap); } while (0)
#define VM4 asm volatile("s_waitcnt vmcnt(4)" ::: "memory")

  f32x4 acc[9][4];
#pragma unroll
  for (int m = 0; m < 9; ++m)
#pragma unroll
    for (int n = 0; n < 4; ++n)
      acc[m][n] = (f32x4){0.f, 0.f, 0.f, 0.f};

  bf16x8 bfr[4][2];
  int cq0 = ((0 * 4 + kg) ^ (fr & 7)) * 8;
  int cq1 = ((1 * 4 + kg) ^ (fr & 7)) * 8;

#define PHASE(b, Q, NM, STAGE, VW) do { \
    bf16x8 af[3][2]; \
    _Pragma("unroll") \
    for (int j = 0; j < (NM); ++j) { \
      int arow = (wr * 144 + ((Q) * 2 + j) * 16 + fr) * 64; \
      af[j][0] = *(const bf16x8*)&Als[(b)][arow + cq0]; \
      af[j][1] = *(const bf16x8*)&Als[(b)][arow + cq1]; \
    } \
    if ((Q) == 0) { \
      _Pragma("unroll") \
      for (int ni = 0; ni < 4; ++ni) { \
        int brow = (wc * 64 + ni * 16 + fr) * 64; \
        bfr[ni][0] = *(const bf16x8*)&Bls[(b)][brow + cq0]; \
        bfr[ni][1] = *(const bf16x8*)&Bls[(b)][brow + cq1]; \
      } \
    } \
    STAGE; \
    VW; \
    __builtin_amdgcn_s_barrier(); \
    __builtin_amdgcn_s_setprio(1); \
    _Pragma("unroll") \
    for (int j = 0; j < (NM); ++j) \
    _Pragma("unroll") \
    for (int ni = 0; ni < 4; ++ni) { \
      acc[(Q) * 2 + j][ni] = __builtin_amdgcn_mfma_f32_16x16x32_bf16(af[j][0], bfr[ni][0], acc[(Q) * 2 + j][ni], 0, 0, 0); \
      acc[(Q) * 2 + j][ni] = __builtin_amdgcn_mfma_f32_16x16x32_bf16(af[j][1], bfr[ni][1], acc[(Q) * 2 + j][ni], 0, 0, 0); \
    } \
    __builtin_amdgcn_s_setprio(0); \
    __builtin_amdgcn_s_barrier(); \
  } while (0)

  const int nt = 16;

  STG_A(0, 0); STG_B0(0, 0); STG_B1(0, 0);
  STG_B0(1, 1); STG_B1(1, 1);
  VM4;
  __builtin_amdgcn_s_barrier();

  for (int j = 0; j < nt / 2; ++j) {
    int t1 = 2 * j + 1, t2 = 2 * j + 2, t3 = 2 * j + 3;
    bool f2 = t2 < nt, f3 = t3 < nt;
    PHASE(0, 0, 2, STG_A(1, t1), (void)0);
    PHASE(0, 1, 2, if (f2) STG_B0(0, t2); else DUM2, (void)0);
    PHASE(0, 2, 2, if (f2) STG_B1(0, t2); else DUM2, (void)0);
    PHASE(0, 3, 3, (void)0, VM4);
    PHASE(1, 0, 2, if (f2) STG_A(0, t2); else DUM5, (void)0);
    PHASE(1, 1, 2, if (f3) STG_B0(1, t3); else DUM2, (void)0);
    PHASE(1, 2, 2, if (f3) STG_B1(1, t3); else DUM2, (void)0);
    PHASE(1, 3, 3, (void)0, VM4);
  }

  int rb = kg * 4;
#pragma unroll
  for (int mi = 0; mi < 9; ++mi) {
#pragma unroll
    for (int r = 0; r < 4; ++r) {
      int row = wr * 144 + mi * 16 + rb + r;
      if (mbase + row < Me) {
        u16* dst = Cmat + (size_t)(off + mbase + row) * CLD + nbase + wc * 64;
#pragma unroll
        for (int ni = 0; ni < 4; ++ni) {
          float v = acc[mi][ni][r];
          if (GELU) v = 0.5f * v * (1.f + erff(v * 0.70710678118654752f));
          dst[ni * 16 + fr] = f2b(v);
        }
      }
    }
  }
#undef STG_A
#undef STG_B0
#undef STG_B1
#undef DUM2
#undef DUM5
#undef VM4
#undef PHASE
}

// ========== fc2 (EXPERIMENT): 288x128 single-buffer 2-barrier GEMM, 2 blocks/CU ==
// BM=288, BN=128, BK=64, K-split 2 (K=1024/block) -> 512 working blocks = 2/CU.
// LDS 52KB single-buffered; plain __syncthreads loop; barrier/stage stalls of one
// block covered by the co-resident block (m97/m114 mechanism). 8 waves 2Mx4N,
// wave tile 144x32 (acc 9x2), launch_bounds(512,4) caps VGPR<=128.
__global__ __launch_bounds__(512, 4) void fc2s_kernel(
    const u16* __restrict__ h, const u16* __restrict__ w2t,
    const int* __restrict__ counts, const int* __restrict__ offsets,
    u16* __restrict__ O)
{
  int bid = blockIdx.x;
  int e, yt, xt, ks;
  if (bid < 512) {
    int t0 = xcd_swz(bid, 512);
    xt = t0 & 7;                 // 8 N-tiles of 128
    ks = (t0 >> 3) & 1;
    yt = (t0 >> 4) & 3;
    e  = t0 >> 6;
  } else {
    int s = bid - 512;           // 128 spares: yt=4
    xt = s & 7;
    ks = (s >> 3) & 1;
    yt = 4;
    e  = s >> 4;
  }

  int Me = counts[e];
  if (Me == 0) return;
  int mbase = yt * 288;
  if (mbase >= Me) return;
  int nbase = xt * 128;
  int off = offsets[e];
  int koff = ks * 1024;
  if (ks == 1) O += (size_t)8192 * DIM;

  __shared__ u16 Als[288 * 64];   // 36 KB
  __shared__ u16 Bls[128 * 64];   // 16 KB
  __shared__ u16 scrap[512];

  int tid = threadIdx.x, lane = tid & 63, wid = tid >> 6;
  int wr = wid >> 2;       // 0..1 (M half: 144 rows)
  int wc = wid & 3;        // 0..3 (N strip: 32 cols)
  int fr = lane & 15, kg = lane >> 4;
  int l8 = lane >> 3, l7 = lane & 7;
  int xorc = (l7 ^ l8) * 8;

  const u16* sA[5];
  const u16* sB[2];
#pragma unroll
  for (int c = 0; c < 4; ++c) {
    int r = (c * 4096 + tid * 8) >> 6;                  // 0..255
    int gr = mbase + r; if (gr >= Me) gr = Me - 1;
    sA[c] = h + (size_t)(off + gr) * FDIM + koff + xorc;
  }
  {
    int r = (tid < 256) ? (256 + (tid >> 3)) : 0;
    int gr = mbase + r; if (gr >= Me) gr = Me - 1;
    sA[4] = h + (size_t)(off + gr) * FDIM + koff + xorc;
  }
#pragma unroll
  for (int c = 0; c < 2; ++c) {
    int r = (c * 4096 + tid * 8) >> 6;                  // 0..127
    sB[c] = w2t + (size_t)e * DIM * FDIM + (size_t)(nbase + r) * FDIM + koff + xorc;
  }
  u16* a4dst = (tid < 256) ? &Als[4 * 4096 + wid * 512] : scrap;

  f32x4 acc[9][2];
#pragma unroll
  for (int m = 0; m < 9; ++m)
#pragma unroll
    for (int n = 0; n < 2; ++n)
      acc[m][n] = (f32x4){0.f, 0.f, 0.f, 0.f};

  int cq0 = ((0 * 4 + kg) ^ (fr & 7)) * 8;
  int cq1 = ((1 * 4 + kg) ^ (fr & 7)) * 8;

  for (int t = 0; t < 16; ++t) {
    __syncthreads();   // prior compute done; safe to overwrite LDS
    size_t kt = (size_t)t * 64;
    GLOAD16(sA[0] + kt, &Als[0 * 4096 + wid * 512]);
    GLOAD16(sA[1] + kt, &Als[1 * 4096 + wid * 512]);
    GLOAD16(sA[2] + kt, &Als[2 * 4096 + wid * 512]);
    GLOAD16(sA[3] + kt, &Als[3 * 4096 + wid * 512]);
    GLOAD16(sA[4] + kt, a4dst);
    GLOAD16(sB[0] + kt, &Bls[0 * 4096 + wid * 512]);
    GLOAD16(sB[1] + kt, &Bls[1 * 4096 + wid * 512]);
    __syncthreads();   // drains vmcnt; tile visible

    bf16x8 bq[2][2];
#pragma unroll
    for (int ni = 0; ni < 2; ++ni) {
      int brow = (wc * 32 + ni * 16 + fr) * 64;
      bq[ni][0] = *(const bf16x8*)&Bls[brow + cq0];
      bq[ni][1] = *(const bf16x8*)&Bls[brow + cq1];
    }
#pragma unroll
    for (int mi = 0; mi < 9; ++mi) {
      int arow = (wr * 144 + mi * 16 + fr) * 64;
      bf16x8 a0 = *(const bf16x8*)&Als[arow + cq0];
      bf16x8 a1 = *(const bf16x8*)&Als[arow + cq1];
#pragma unroll
      for (int ni = 0; ni < 2; ++ni) {
        acc[mi][ni] = __builtin_amdgcn_mfma_f32_16x16x32_bf16(a0, bq[ni][0], acc[mi][ni], 0, 0, 0);
        acc[mi][ni] = __builtin_amdgcn_mfma_f32_16x16x32_bf16(a1, bq[ni][1], acc[mi][ni], 0, 0, 0);
      }
    }
  }

  int rb = kg * 4;
#pragma unroll
  for (int mi = 0; mi < 9; ++mi) {
#pragma unroll
    for (int r = 0; r < 4; ++r) {
      int row = wr * 144 + mi * 16 + rb + r;
      if (mbase + row < Me) {
        u16* dst = O + (size_t)(off + mbase + row) * DIM + nbase + wc * 32;
#pragma unroll
        for (int ni = 0; ni < 2; ++ni)
          dst[ni * 16 + fr] = f2b(acc[mi][ni][r]);
      }
    }
  }
}

// ---------------- combine: y[t] = w0*(O0[s0]+O1[s0]) + w1*(O0[s1]+O1[s1]) --------
__global__ __launch_bounds__(256) void combine_kernel(
    const u16* __restrict__ O, const int* __restrict__ slot,
    const float* __restrict__ tokwgt, float* __restrict__ y)
{
  int idx = blockIdx.x * 256 + threadIdx.x;
  int t = idx >> 7;
  int d8 = (idx & 127) << 3;
  int s0 = slot[2 * t], s1 = slot[2 * t + 1];
  float w0 = tokwgt[2 * t], w1 = tokwgt[2 * t + 1];
  const u16* O1p = O + (size_t)8192 * DIM;
  bf16x8 a0 = *(const bf16x8*)(O + (size_t)s0 * DIM + d8);
  bf16x8 a1 = *(const bf16x8*)(O1p + (size_t)s0 * DIM + d8);
  bf16x8 b0 = *(const bf16x8*)(O + (size_t)s1 * DIM + d8);
  bf16x8 b1 = *(const bf16x8*)(O1p + (size_t)s1 * DIM + d8);
  float* dst = y + (size_t)t * DIM + d8;
  float4 o0, o1;
  o0.x = w0 * ((float)a0[0] + (float)a1[0]) + w1 * ((float)b0[0] + (float)b1[0]);
  o0.y = w0 * ((float)a0[1] + (float)a1[1]) + w1 * ((float)b0[1] + (float)b1[1]);
  o0.z = w0 * ((float)a0[2] + (float)a1[2]) + w1 * ((float)b0[2] + (float)b1[2]);
  o0.w = w0 * ((float)a0[3] + (float)a1[3]) + w1 * ((float)b0[3] + (float)b1[3]);
  o1.x = w0 * ((float)a0[4] + (float)a1[4]) + w1 * ((float)b0[4] + (float)b1[4]);
  o1.y = w0 * ((float)a0[5] + (float)a1[5]) + w1 * ((float)b0[5] + (float)b1[5]);
  o1.z = w0 * ((float)a0[6] + (float)a1[6]) + w1 * ((float)b0[6] + (float)b1[6]);
  o1.w = w0 * ((float)a0[7] + (float)a1[7]) + w1 * ((float)b0[7] + (float)b1[7]);
  *(float4*)dst = o0;
  *(float4*)(dst + 4) = o1;
}

extern "C" void kernel_launch(void* const* d_in, const int* in_sizes, int n_in,
                              void* d_out, int out_size, void* d_ws, size_t ws_size,
                              hipStream_t stream)
{
  const float* x  = (const float*)d_in[0];
  const float* wg = (const float*)d_in[1];
  const float* w1 = (const float*)d_in[2];
  const float* w2 = (const float*)d_in[3];
  float* y = (float*)d_out;

  char* ws = (char*)d_ws;
  size_t o = 0;
  u16* h      = (u16*)(ws + o);   o += (size_t)8192 * FDIM * 2;        // 33.55 MB
  u16* w2t    = (u16*)(ws + o);   o += (size_t)NEXP * DIM * FDIM * 2;  // 33.55 MB
  u16* xb     = (u16*)(ws + o);   o += (size_t)T_TOK * DIM * 2;        //  8.39 MB
  u16* w1b    = (u16*)(ws + o);   o += (size_t)NEXP * FDIM * DIM * 2;  // 33.55 MB
  u16* O      = w1b;  // aliased: w1b dead after fc1; O = 2 x [8192][DIM] bf16
  int*   tokexp = (int*)(ws + o); o += (size_t)T_TOK * 2 * 4;
  float* tokwgt = (float*)(ws + o); o += (size_t)T_TOK * 2 * 4;
  int*   tok    = (int*)(ws + o); o += (size_t)T_TOK * 2 * 4;
  int*   slot   = (int*)(ws + o); o += (size_t)T_TOK * 2 * 4;
  int*   counts = (int*)(ws + o); o += 128;
  int*   offsets= (int*)(ws + o); o += 128;

  gating_kernel<<<T_TOK / 4, 256, 0, stream>>>(x, wg, tokexp, tokwgt, xb);
  plan_kernel<<<1, 256, 0, stream>>>(tokexp, counts, offsets, tok, slot);

  prep_kernel<<<8192 + 4096, 256, 0, stream>>>(w1, w1b, w2, w2t);

  // fc1 (control): r8 8-phase 288x256
  gemm8_kernel<1, 1, DIM, DIM, 8, 1, FDIM>
      <<<320, 512, 0, stream>>>(xb, w1b, tok, counts, offsets, h);
  // fc2 (experiment): 288x128 single-buffer, 2 blocks/CU, 512 working blocks
  fc2s_kernel<<<640, 512, 0, stream>>>(h, w2t, counts, offsets, O);

  combine_kernel<<<T_TOK * DIM / 8 / 256, 256, 0, stream>>>(O, slot, tokwgt, y);
}

// Round 12
// 164.973 us; speedup vs baseline: 1.1023x; 1.0171x over previous
//
#include <hip/hip_runtime.h>

#define T_TOK 4096
#define DIM   1024
#define FDIM  2048
#define NEXP  8

typedef unsigned short u16;
typedef unsigned int   u32;
typedef __bf16 bf16x8 __attribute__((ext_vector_type(8)));
typedef float  f32x4  __attribute__((ext_vector_type(4)));

__device__ __forceinline__ u16 f2b(float f) {
  __bf16 b = (__bf16)f;
  return __builtin_bit_cast(u16, b);
}
__device__ __forceinline__ u32 pk(float a, float b) {
  return (u32)f2b(a) | ((u32)f2b(b) << 16);
}

#define GLOAD16(gsrc, ldst) \
  __builtin_amdgcn_global_load_lds((const __attribute__((address_space(1))) void*)(gsrc), \
                                   (__attribute__((address_space(3))) void*)(ldst), 16, 0, 0)

__device__ __forceinline__ int xcd_swz(int b, int nwg) {
  return (b & 7) * (nwg >> 3) + (b >> 3);
}

// ------- fused gating (blocks 0..1023) + w1 convert (1024..9215) + w2 transpose --
__global__ __launch_bounds__(256) void prep_kernel(
    const float* __restrict__ x, const float* __restrict__ wg,
    int* __restrict__ tokexp, float* __restrict__ tokwgt, u16* __restrict__ xb,
    const float* __restrict__ w1, u16* __restrict__ w1b,
    const float* __restrict__ w2, u16* __restrict__ w2t)
{
  __shared__ float tile[64][65];
  int b = blockIdx.x;
  int tid = threadIdx.x;

  if (b < 1024) {
    // ---- gating: 1 token per wave; logits -> softmax -> top2; fused x->bf16
    int wid = tid >> 6, lane = tid & 63;
    int t = b * 4 + wid;
    const float4* xr = (const float4*)(x + (size_t)t * DIM) + lane * 4;
    float4 xv[4];
#pragma unroll
    for (int j = 0; j < 4; ++j) xv[j] = xr[j];

    u16* xd = xb + (size_t)t * DIM + lane * 16;
    uint4 lo, hi;
    lo.x = pk(xv[0].x, xv[0].y); lo.y = pk(xv[0].z, xv[0].w);
    lo.z = pk(xv[1].x, xv[1].y); lo.w = pk(xv[1].z, xv[1].w);
    hi.x = pk(xv[2].x, xv[2].y); hi.y = pk(xv[2].z, xv[2].w);
    hi.z = pk(xv[3].x, xv[3].y); hi.w = pk(xv[3].z, xv[3].w);
    *(uint4*)xd = lo;
    *(uint4*)(xd + 8) = hi;

    float logit[NEXP];
#pragma unroll
    for (int e = 0; e < NEXP; ++e) {
      const float4* wr = (const float4*)(wg + (size_t)e * DIM) + lane * 4;
      float s = 0.f;
#pragma unroll
      for (int j = 0; j < 4; ++j) {
        float4 wv = wr[j];
        s += xv[j].x * wv.x + xv[j].y * wv.y + xv[j].z * wv.z + xv[j].w * wv.w;
      }
#pragma unroll
      for (int d = 32; d > 0; d >>= 1) s += __shfl_down(s, d, 64);
      logit[e] = s;
    }
    if (lane == 0) {
      float mx = -1e30f;
#pragma unroll
      for (int e = 0; e < NEXP; ++e) mx = fmaxf(mx, logit[e]);
      float p[NEXP]; float s = 0.f;
#pragma unroll
      for (int e = 0; e < NEXP; ++e) { p[e] = expf(logit[e] - mx); s += p[e]; }
      float inv = 1.f / s;
#pragma unroll
      for (int e = 0; e < NEXP; ++e) p[e] *= inv;
      int e0 = 0;
#pragma unroll
      for (int e = 1; e < NEXP; ++e) if (p[e] > p[e0]) e0 = e;
      int e1 = (e0 == 0) ? 1 : 0;
#pragma unroll
      for (int e = 0; e < NEXP; ++e) if (e != e0 && p[e] > p[e1]) e1 = e;
      tokexp[2 * t]     = e0;
      tokexp[2 * t + 1] = e1;
      tokwgt[2 * t]     = p[e0];
      tokwgt[2 * t + 1] = p[e1];
    }
    return;
  }

  if (b < 1024 + 8192) {
    // ---- w1 fp32 -> bf16
    size_t i = (size_t)(b - 1024) * 256 + tid;
    const float4* s = (const float4*)(w1 + i * 8);
    float4 v0 = s[0], v1 = s[1];
    uint4 w;
    w.x = pk(v0.x, v0.y); w.y = pk(v0.z, v0.w);
    w.z = pk(v1.x, v1.y); w.w = pk(v1.z, v1.w);
    *(uint4*)(w1b + i * 8) = w;
    return;
  }

  // ---- w2 [E][F][D] fp32 -> w2t [E][D][F] bf16, 64x64 tiles
  int bb = b - (1024 + 8192);
  int e = bb >> 9;
  int r = bb & 511;
  int d0 = (r & 15) * 64;
  int f0 = (r >> 4) * 64;
  int fi = tid >> 2;
  int c4 = tid & 3;
  const float* src = w2 + ((size_t)e * FDIM + f0 + fi) * DIM + d0;
#pragma unroll
  for (int i = 0; i < 4; ++i) {
    int col = (c4 + i * 4) * 4;
    float4 v = *(const float4*)(src + col);
    tile[fi][col] = v.x; tile[fi][col + 1] = v.y;
    tile[fi][col + 2] = v.z; tile[fi][col + 3] = v.w;
  }
  __syncthreads();
  u16* dst = w2t + ((size_t)e * DIM + d0) * FDIM + f0;
#pragma unroll
  for (int i = 0; i < 2; ++i) {
    int id = i * 256 + tid;
    int d = id >> 3;
    int c = id & 7;
    uint4 w;
    w.x = pk(tile[c * 8 + 0][d], tile[c * 8 + 1][d]);
    w.y = pk(tile[c * 8 + 2][d], tile[c * 8 + 3][d]);
    w.z = pk(tile[c * 8 + 4][d], tile[c * 8 + 5][d]);
    w.w = pk(tile[c * 8 + 6][d], tile[c * 8 + 7][d]);
    *(uint4*)(dst + (size_t)d * FDIM + c * 8) = w;
  }
}

// ---------------- plan: single block; histogram + offsets + stable scatter --------
__global__ __launch_bounds__(256) void plan_kernel(
    const int* __restrict__ tokexp,
    int* __restrict__ counts, int* __restrict__ offsets,
    int* __restrict__ tok, int* __restrict__ slot)
{
  __shared__ int hist[256][NEXP];
  __shared__ int soff[NEXP];
  int tid = threadIdx.x;
  int ex[32];
  int loc[NEXP];
#pragma unroll
  for (int e = 0; e < NEXP; ++e) loc[e] = 0;
#pragma unroll
  for (int j = 0; j < 32; ++j) {
    ex[j] = tokexp[tid * 32 + j];
#pragma unroll
    for (int e = 0; e < NEXP; ++e) loc[e] += (ex[j] == e);
  }
#pragma unroll
  for (int e = 0; e < NEXP; ++e) hist[tid][e] = loc[e];
  __syncthreads();
  if (tid < NEXP) {
    int s = 0;
    for (int i = 0; i < 256; ++i) { int v = hist[i][tid]; hist[i][tid] = s; s += v; }
    counts[tid] = s;
  }
  __syncthreads();
  if (tid == 0) {
    int s = 0;
#pragma unroll
    for (int e = 0; e < NEXP; ++e) { soff[e] = s; offsets[e] = s; s += counts[e]; }
  }
  __syncthreads();
  int cur[NEXP];
#pragma unroll
  for (int e = 0; e < NEXP; ++e) cur[e] = soff[e] + hist[tid][e];
#pragma unroll
  for (int j = 0; j < 32; ++j) {
    int a = tid * 32 + j;
    int r = 0;
#pragma unroll
    for (int e = 0; e < NEXP; ++e) if (ex[j] == e) r = cur[e]++;
    tok[r] = a >> 1;
    slot[a] = r;
  }
}

// ========== grouped 288x256 8-phase GEMM (16x16x32 MFMA, K per block = 1024) =====
// r8-proven config; K-loop tail PEELED so the steady-state body is branch-free.
template<int GELU, int GATHER, int KA, int KB, int NT, int KS, int CLD>
__global__ __launch_bounds__(512, 2) void gemm8_kernel(
    const u16* __restrict__ Amat, const u16* __restrict__ Bmat,
    const int* __restrict__ tok, const int* __restrict__ counts,
    const int* __restrict__ offsets, u16* __restrict__ Cmat)
{
  const int NTK = NT * KS;
  int bid = blockIdx.x;
  int e, yt, xt, ks;
  if (bid < 256) {
    int t0 = xcd_swz(bid, 256);
    xt = t0 % NT;
    ks = (t0 / NT) % KS;
    yt = (t0 / NTK) & 3;
    e  = t0 / (NTK * 4);
  } else {
    int s = bid - 256;
    xt = s % NT;
    ks = (s / NT) % KS;
    yt = 4;
    e  = s / NTK;
  }

  int Me = counts[e];
  if (Me == 0) return;
  int mbase = yt * 288;
  if (mbase >= Me) return;
  int nbase = xt * 256;
  int off = offsets[e];
  int koff = ks * 1024;
  if (KS == 2 && ks == 1) Cmat += (size_t)8192 * CLD;

  __shared__ u16 Als[2][288 * 64];
  __shared__ u16 Bls[2][256 * 64];
  __shared__ u16 scrap[512];

  int tid = threadIdx.x, lane = tid & 63, wid = tid >> 6;
  int wr = wid >> 2;
  int wc = wid & 3;
  int fr = lane & 15, kg = lane >> 4;
  int l8 = lane >> 3, l7 = lane & 7;
  int xorc = (l7 ^ l8) * 8;

  const u16* sA[5];
  const u16* sB[4];
#pragma unroll
  for (int c = 0; c < 4; ++c) {
    int r = (c * 4096 + tid * 8) >> 6;
    int gr = mbase + r; if (gr >= Me) gr = Me - 1;
    int arow = GATHER ? tok[off + gr] : (off + gr);
    sA[c] = Amat + (size_t)arow * KA + koff + xorc;
    sB[c] = Bmat + (size_t)e * FDIM * DIM + (size_t)(nbase + r) * KB + koff + xorc;
  }
  {
    int r = (tid < 256) ? (256 + (tid >> 3)) : 0;
    int gr = mbase + r; if (gr >= Me) gr = Me - 1;
    int arow = GATHER ? tok[off + gr] : (off + gr);
    sA[4] = Amat + (size_t)arow * KA + koff + xorc;
  }
  int a4real = (tid < 256);
  u16* a4dst[2];
  a4dst[0] = a4real ? &Als[0][4 * 4096 + wid * 512] : scrap;
  a4dst[1] = a4real ? &Als[1][4 * 4096 + wid * 512] : scrap;

#define STG_A(b, t_) do { \
    GLOAD16(sA[0] + (size_t)(t_) * 64, &Als[(b)][0 * 4096 + wid * 512]); \
    GLOAD16(sA[1] + (size_t)(t_) * 64, &Als[(b)][1 * 4096 + wid * 512]); \
    GLOAD16(sA[2] + (size_t)(t_) * 64, &Als[(b)][2 * 4096 + wid * 512]); \
    GLOAD16(sA[3] + (size_t)(t_) * 64, &Als[(b)][3 * 4096 + wid * 512]); \
    GLOAD16(sA[4] + (size_t)(t_) * 64, a4dst[(b)]); } while (0)
#define STG_B0(b, t_) do { \
    GLOAD16(sB[0] + (size_t)(t_) * 64, &Bls[(b)][0 * 4096 + wid * 512]); \
    GLOAD16(sB[1] + (size_t)(t_) * 64, &Bls[(b)][1 * 4096 + wid * 512]); } while (0)
#define STG_B1(b, t_) do { \
    GLOAD16(sB[2] + (size_t)(t_) * 64, &Bls[(b)][2 * 4096 + wid * 512]); \
    GLOAD16(sB[3] + (size_t)(t_) * 64, &Bls[(b)][3 * 4096 + wid * 512]); } while (0)
#define DUM2 do { GLOAD16(sA[0], scrap); GLOAD16(sA[0], scrap); } while (0)
#define DUM5 do { DUM2; DUM2; GLOAD16(sA[0], scrap); } while (0)
#define VM4 asm volatile("s_waitcnt vmcnt(4)" ::: "memory")

  f32x4 acc[9][4];
#pragma unroll
  for (int m = 0; m < 9; ++m)
#pragma unroll
    for (int n = 0; n < 4; ++n)
      acc[m][n] = (f32x4){0.f, 0.f, 0.f, 0.f};

  bf16x8 bfr[4][2];
  int cq0 = ((0 * 4 + kg) ^ (fr & 7)) * 8;
  int cq1 = ((1 * 4 + kg) ^ (fr & 7)) * 8;

#define PHASE(b, Q, NM, STAGE, VW) do { \
    bf16x8 af[3][2]; \
    _Pragma("unroll") \
    for (int j = 0; j < (NM); ++j) { \
      int arow = (wr * 144 + ((Q) * 2 + j) * 16 + fr) * 64; \
      af[j][0] = *(const bf16x8*)&Als[(b)][arow + cq0]; \
      af[j][1] = *(const bf16x8*)&Als[(b)][arow + cq1]; \
    } \
    if ((Q) == 0) { \
      _Pragma("unroll") \
      for (int ni = 0; ni < 4; ++ni) { \
        int brow = (wc * 64 + ni * 16 + fr) * 64; \
        bfr[ni][0] = *(const bf16x8*)&Bls[(b)][brow + cq0]; \
        bfr[ni][1] = *(const bf16x8*)&Bls[(b)][brow + cq1]; \
      } \
    } \
    STAGE; \
    VW; \
    __builtin_amdgcn_s_barrier(); \
    __builtin_amdgcn_s_setprio(1); \
    _Pragma("unroll") \
    for (int j = 0; j < (NM); ++j) \
    _Pragma("unroll") \
    for (int ni = 0; ni < 4; ++ni) { \
      acc[(Q) * 2 + j][ni] = __builtin_amdgcn_mfma_f32_16x16x32_bf16(af[j][0], bfr[ni][0], acc[(Q) * 2 + j][ni], 0, 0, 0); \
      acc[(Q) * 2 + j][ni] = __builtin_amdgcn_mfma_f32_16x16x32_bf16(af[j][1], bfr[ni][1], acc[(Q) * 2 + j][ni], 0, 0, 0); \
    } \
    __builtin_amdgcn_s_setprio(0); \
    __builtin_amdgcn_s_barrier(); \
  } while (0)

  const int nt = 16;

  STG_A(0, 0); STG_B0(0, 0); STG_B1(0, 0);
  STG_B0(1, 1); STG_B1(1, 1);
  VM4;
  __builtin_amdgcn_s_barrier();

  // steady state: branch-free (t2 = 2j+2 <= 14, t3 = 2j+3 <= 15 all valid)
  for (int j = 0; j < nt / 2 - 1; ++j) {
    int t1 = 2 * j + 1, t2 = 2 * j + 2, t3 = 2 * j + 3;
    PHASE(0, 0, 2, STG_A(1, t1), (void)0);
    PHASE(0, 1, 2, STG_B0(0, t2), (void)0);
    PHASE(0, 2, 2, STG_B1(0, t2), (void)0);
    PHASE(0, 3, 3, (void)0, VM4);
    PHASE(1, 0, 2, STG_A(0, t2), (void)0);
    PHASE(1, 1, 2, STG_B0(1, t3), (void)0);
    PHASE(1, 2, 2, STG_B1(1, t3), (void)0);
    PHASE(1, 3, 3, (void)0, VM4);
  }
  // peeled tail (j = nt/2-1): t1 = 15 valid; t2,t3 out of range -> dummies
  PHASE(0, 0, 2, STG_A(1, 15), (void)0);
  PHASE(0, 1, 2, DUM2, (void)0);
  PHASE(0, 2, 2, DUM2, (void)0);
  PHASE(0, 3, 3, (void)0, VM4);
  PHASE(1, 0, 2, DUM5, (void)0);
  PHASE(1, 1, 2, DUM2, (void)0);
  PHASE(1, 2, 2, DUM2, (void)0);
  PHASE(1, 3, 3, (void)0, VM4);

  int rb = kg * 4;
#pragma unroll
  for (int mi = 0; mi < 9; ++mi) {
#pragma unroll
    for (int r = 0; r < 4; ++r) {
      int row = wr * 144 + mi * 16 + rb + r;
      if (mbase + row < Me) {
        u16* dst = Cmat + (size_t)(off + mbase + row) * CLD + nbase + wc * 64;
#pragma unroll
        for (int ni = 0; ni < 4; ++ni) {
          float v = acc[mi][ni][r];
          if (GELU) v = 0.5f * v * (1.f + erff(v * 0.70710678118654752f));
          dst[ni * 16 + fr] = f2b(v);
        }
      }
    }
  }
#undef STG_A
#undef STG_B0
#undef STG_B1
#undef DUM2
#undef DUM5
#undef VM4
#undef PHASE
}

// ---------------- combine: y[t] = w0*(O0[s0]+O1[s0]) + w1*(O0[s1]+O1[s1]) --------
__global__ __launch_bounds__(256) void combine_kernel(
    const u16* __restrict__ O, const int* __restrict__ slot,
    const float* __restrict__ tokwgt, float* __restrict__ y)
{
  int idx = blockIdx.x * 256 + threadIdx.x;
  int t = idx >> 7;
  int d8 = (idx & 127) << 3;
  int s0 = slot[2 * t], s1 = slot[2 * t + 1];
  float w0 = tokwgt[2 * t], w1 = tokwgt[2 * t + 1];
  const u16* O1p = O + (size_t)8192 * DIM;
  bf16x8 a0 = *(const bf16x8*)(O + (size_t)s0 * DIM + d8);
  bf16x8 a1 = *(const bf16x8*)(O1p + (size_t)s0 * DIM + d8);
  bf16x8 b0 = *(const bf16x8*)(O + (size_t)s1 * DIM + d8);
  bf16x8 b1 = *(const bf16x8*)(O1p + (size_t)s1 * DIM + d8);
  float* dst = y + (size_t)t * DIM + d8;
  float4 o0, o1;
  o0.x = w0 * ((float)a0[0] + (float)a1[0]) + w1 * ((float)b0[0] + (float)b1[0]);
  o0.y = w0 * ((float)a0[1] + (float)a1[1]) + w1 * ((float)b0[1] + (float)b1[1]);
  o0.z = w0 * ((float)a0[2] + (float)a1[2]) + w1 * ((float)b0[2] + (float)b1[2]);
  o0.w = w0 * ((float)a0[3] + (float)a1[3]) + w1 * ((float)b0[3] + (float)b1[3]);
  o1.x = w0 * ((float)a0[4] + (float)a1[4]) + w1 * ((float)b0[4] + (float)b1[4]);
  o1.y = w0 * ((float)a0[5] + (float)a1[5]) + w1 * ((float)b0[5] + (float)b1[5]);
  o1.z = w0 * ((float)a0[6] + (float)a1[6]) + w1 * ((float)b0[6] + (float)b1[6]);
  o1.w = w0 * ((float)a0[7] + (float)a1[7]) + w1 * ((float)b0[7] + (float)b1[7]);
  *(float4*)dst = o0;
  *(float4*)(dst + 4) = o1;
}

extern "C" void kernel_launch(void* const* d_in, const int* in_sizes, int n_in,
                              void* d_out, int out_size, void* d_ws, size_t ws_size,
                              hipStream_t stream)
{
  const float* x  = (const float*)d_in[0];
  const float* wg = (const float*)d_in[1];
  const float* w1 = (const float*)d_in[2];
  const float* w2 = (const float*)d_in[3];
  float* y = (float*)d_out;

  char* ws = (char*)d_ws;
  size_t o = 0;
  u16* h      = (u16*)(ws + o);   o += (size_t)8192 * FDIM * 2;        // 33.55 MB
  u16* w2t    = (u16*)(ws + o);   o += (size_t)NEXP * DIM * FDIM * 2;  // 33.55 MB
  u16* xb     = (u16*)(ws + o);   o += (size_t)T_TOK * DIM * 2;        //  8.39 MB
  u16* w1b    = (u16*)(ws + o);   o += (size_t)NEXP * FDIM * DIM * 2;  // 33.55 MB
  u16* O      = w1b;  // aliased: w1b dead after fc1; O = 2 x [8192][DIM] bf16
  int*   tokexp = (int*)(ws + o); o += (size_t)T_TOK * 2 * 4;
  float* tokwgt = (float*)(ws + o); o += (size_t)T_TOK * 2 * 4;
  int*   tok    = (int*)(ws + o); o += (size_t)T_TOK * 2 * 4;
  int*   slot   = (int*)(ws + o); o += (size_t)T_TOK * 2 * 4;
  int*   counts = (int*)(ws + o); o += 128;
  int*   offsets= (int*)(ws + o); o += 128;

  // gating (1024) + w1 convert (8192) + w2 transpose (4096) fused
  prep_kernel<<<1024 + 8192 + 4096, 256, 0, stream>>>(
      x, wg, tokexp, tokwgt, xb, w1, w1b, w2, w2t);
  plan_kernel<<<1, 256, 0, stream>>>(tokexp, counts, offsets, tok, slot);

  // fc1: h = gelu(gather(xb) @ w1b^T)   [NT=8, KS=1]
  gemm8_kernel<1, 1, DIM, DIM, 8, 1, FDIM>
      <<<320, 512, 0, stream>>>(xb, w1b, tok, counts, offsets, h);
  // fc2: O[ks] = h[:, ks*1024:+1024] @ w2t[:, ks*1024:+1024]^T  [NT=4, KS=2]
  gemm8_kernel<0, 0, FDIM, FDIM, 4, 2, DIM>
      <<<320, 512, 0, stream>>>(h, w2t, tok, counts, offsets, O);

  combine_kernel<<<T_TOK * DIM / 8 / 256, 256, 0, stream>>>(O, slot, tokwgt, y);
}